// Round 1
// baseline (564.493 us; speedup 1.0000x reference)
//
#include <hip/hip_runtime.h>
#include <hip/hip_bf16.h>
#include <math.h>

// Problem: B=8, S=512, V=32000, M=32, PAD_ID=1
// logp[b,s] = logits[b,s,a[b,s]] - logsumexp_{m: mask[b,s,m]>0}(logits[b,s,mask[b,s,m]])
// out[b] = sum_s logp[b,s] * (a[b,s] != 1)
// Softmax Z cancels in p_a/base -> no need to read the V dimension.

#define BB 8
#define SS 512
#define VV 32000
#define MM 32

__global__ void init_out_kernel(float* out) {
    if (threadIdx.x < BB) out[threadIdx.x] = 0.0f;
}

__global__ __launch_bounds__(256) void logp_kernel(
    const float* __restrict__ logits,   // [B*S, V]
    const int*   __restrict__ a,        // [B*S]
    const int*   __restrict__ mask,     // [B*S, M]
    float*       __restrict__ out)      // [B]
{
    const int wave = threadIdx.x >> 6;          // 0..3
    const int lane = threadIdx.x & 63;
    const int pos  = (blockIdx.x << 2) + wave;  // 0..B*S-1
    const int b    = pos >> 9;                  // pos / 512

    const float* __restrict__ row = logits + (size_t)pos * VV;

    // Issue the action-logit load early so it overlaps the reduction.
    const int aid = a[pos];
    const float logit_a = row[aid];

    // Lanes 0..31 gather masked logits; invalid/inactive lanes contribute
    // -inf to the max and 0 to the sum.
    float x = -INFINITY;
    if (lane < MM) {
        const int m = mask[pos * MM + lane];
        if (m > 0) x = row[m];
    }

    // Wave max (64-lane butterfly; lanes >=32 hold -inf).
    float mx = x;
    #pragma unroll
    for (int off = 32; off; off >>= 1)
        mx = fmaxf(mx, __shfl_xor(mx, off, 64));

    // Wave sum of exp(x - mx).
    float e = (x == -INFINITY) ? 0.0f : expf(x - mx);
    #pragma unroll
    for (int off = 32; off; off >>= 1)
        e += __shfl_xor(e, off, 64);

    const float lse  = mx + logf(e);
    const float logp = (aid != 1) ? (logit_a - lse) : 0.0f;

    // 4 waves per block, all same b (512 % 4 == 0): LDS reduce, one atomic.
    __shared__ float ws[4];
    if (lane == 0) ws[wave] = logp;
    __syncthreads();
    if (threadIdx.x == 0) {
        const float s = ws[0] + ws[1] + ws[2] + ws[3];
        atomicAdd(&out[b], s);
    }
}

extern "C" void kernel_launch(void* const* d_in, const int* in_sizes, int n_in,
                              void* d_out, int out_size, void* d_ws, size_t ws_size,
                              hipStream_t stream) {
    const float* logits = (const float*)d_in[0];
    const int*   a      = (const int*)d_in[1];
    const int*   mask   = (const int*)d_in[2];
    float*       out    = (float*)d_out;

    init_out_kernel<<<1, 64, 0, stream>>>(out);

    const int n_pos  = BB * SS;            // 4096 positions
    const int blocks = n_pos / 4;          // 4 waves (positions) per block
    logp_kernel<<<blocks, 256, 0, stream>>>(logits, a, mask, out);
}